// Round 7
// baseline (49.550 us; speedup 1.0000x reference)
//
#include <hip/hip_runtime.h>
#include <hip/hip_cooperative_groups.h>
#include <stdint.h>

// TripletLoss on MI355X. E=8192, N=2048, K=8, L=16, top-400 of Gumbel-perturbed logw.
// Round 7: ONE cooperative dispatch. 64 blocks x 1024: per-edge gather/bc/flags
// spread over 64 CUs (round 5 proved 1 CU = 35us gather wall), grid.sync(),
// then block 0 runs the validated fused pipeline (packed scans -> CSR -> one
// thread/pair -> 4-pass radix threshold -> deterministic reduce) with candidates
// held in 4 registers/thread (no global cand round-trips; spill path for safety).

namespace cg = cooperative_groups;

#define E_CONST 8192
#define N_CONST 2048
#define K_CONST 8
#define L_CONST 16
#define MAXS 400
#define EPS_F 1e-9f
#define NTHR 1024
#define PREP_BLOCKS 64
#define EDGES_PER_BLK (E_CONST / PREP_BLOCKS)  // 128
#define RCAP 4096  // register-resident candidates (4 per thread)

struct Cand { float val; uint32_t pack; };

// ---- threefry2x32, key = jax.random.key(42), partitionable path (validated absmax 0.0) ----
__device__ __forceinline__ uint2 threefry2x32_42(uint32_t x0, uint32_t x1) {
    const uint32_t ks0 = 0u, ks1 = 42u;
    const uint32_t ks2 = ks0 ^ ks1 ^ 0x1BD11BDAu;
    const uint32_t ks[3] = {ks0, ks1, ks2};
    const int R[2][4] = {{13, 15, 26, 6}, {17, 29, 16, 24}};
    x0 += ks0; x1 += ks1;
#pragma unroll
    for (int g = 0; g < 5; ++g) {
        const int* r = R[g & 1];
#pragma unroll
        for (int q = 0; q < 4; ++q) {
            x0 += x1;
            x1 = (x1 << r[q]) | (x1 >> (32 - r[q]));
            x1 ^= x0;
        }
        x0 += ks[(g + 1) % 3];
        x1 += ks[(g + 2) % 3] + (uint32_t)(g + 1);
    }
    return make_uint2(x0, x1);
}

__device__ __forceinline__ float gumbel_at(uint32_t idx) {
    uint2 o = threefry2x32_42(0u, idx);
    uint32_t bits = o.x ^ o.y;
    float u = __uint_as_float((bits >> 9) | 0x3F800000u) - 1.0f;
    return -logf(-logf(u + EPS_F) + EPS_F);
}

__device__ __forceinline__ uint32_t sortable_key(float f) {
    uint32_t b = __float_as_uint(f);
    return (b & 0x80000000u) ? ~b : (b | 0x80000000u);
}

__device__ __forceinline__ int argmax8(float4 a, float4 b) {
    float v[8] = {a.x, a.y, a.z, a.w, b.x, b.y, b.z, b.w};
    float best = v[0]; int bi = 0;
#pragma unroll
    for (int k = 1; k < 8; ++k)
        if (v[k] > best) { best = v[k]; bi = k; }  // first-max == jnp.argmax
    return bi;
}

// exclusive in-place scan of arr[2048] by 1024 threads (each owns 2 elems).
// Works for 16|16-bit packed fields: per-field totals < 65536 -> no cross-field carry.
__device__ __forceinline__ void scan_inplace(int* arr, int* tmp, int* totalOut) {
    int tid = threadIdx.x;
    int lane = tid & 63, wid = tid >> 6;
    int i0 = 2 * tid, i1 = i0 + 1;
    int v0 = arr[i0], v1 = arr[i1];
    int s = v0 + v1;
    int inc = s;
#pragma unroll
    for (int off = 1; off < 64; off <<= 1) {
        int u = __shfl_up(inc, off);
        if (lane >= off) inc += u;
    }
    if (lane == 63) tmp[wid] = inc;
    __syncthreads();
    if (wid == 0) {
        int w = (lane < 16) ? tmp[lane] : 0;
        int incw = w;
#pragma unroll
        for (int off = 1; off < 16; off <<= 1) {
            int u = __shfl_up(incw, off);
            if (lane >= off) incw += u;
        }
        if (lane < 16) tmp[lane] = incw - w;  // exclusive wave bases
    }
    __syncthreads();
    int base = tmp[wid] + (inc - s);
    arr[i0] = base;
    arr[i1] = base + v0;
    if (tid == 1023) *totalOut = base + v0 + v1;
    __syncthreads();
}

__global__ __launch_bounds__(1024) void k_all(
    const float* __restrict__ probas, const float* __restrict__ clusters,
    const int* __restrict__ edges, const int* __restrict__ keypts,
    float* __restrict__ bc, unsigned char* __restrict__ flags,
    Cand* __restrict__ spill, int pmax, float* __restrict__ out) {

    __shared__ int s_pk[N_CONST];        // packed cnt (P low16 | N high16) -> packed base
    __shared__ int s_q[N_CONST];         // pair cnt -> pair base
    __shared__ int s_cur[N_CONST];       // packed fill cursors
    __shared__ uint16_t s_csr[E_CONST];  // pos entries [0,nPosTot), neg at nPosTot+
    __shared__ int s_tmp[16];
    __shared__ int s_hist[256];
    __shared__ float s_wsum[16];
    __shared__ int s_wcnt[16];
    __shared__ uint32_t s_mask;
    __shared__ int s_totPk, s_totQ;
    __shared__ uint32_t s_prefix;
    __shared__ int s_target;

    int tid = threadIdx.x;

    // ===== prep phase: all 64 blocks, gathers spread over 64 CUs =====
    if (tid == 0) s_mask = 0;
    __syncthreads();
    if (tid < L_CONST) {
        const float4* r = (const float4*)(clusters + keypts[tid] * K_CONST);
        atomicOr(&s_mask, 1u << argmax8(r[0], r[1]));
    }
    __syncthreads();
    uint32_t m = s_mask;
    if (tid < EDGES_PER_BLK) {
        int e = blockIdx.x * EDGES_PER_BLK + tid;
        const int2* ed2 = (const int2*)edges;
        const float4* c4 = (const float4*)clusters;
        int2 p = ed2[e];
        float4 a0 = c4[2 * p.x], a1 = c4[2 * p.x + 1];
        float4 b0 = c4[2 * p.y], b1 = c4[2 * p.y + 1];
        int c0 = argmax8(a0, a1);
        int c1 = argmax8(b0, b1);
        float s = sqrtf(a0.x * b0.x);       // k ascending, matches ref reduce order
        s += sqrtf(a0.y * b0.y);
        s += sqrtf(a0.z * b0.z);
        s += sqrtf(a0.w * b0.w);
        s += sqrtf(a1.x * b1.x);
        s += sqrtf(a1.y * b1.y);
        s += sqrtf(a1.z * b1.z);
        s += sqrtf(a1.w * b1.w);
        bc[e] = s;
        unsigned char f = 0;
        if ((((m >> c0) | (m >> c1)) & 1u)) f = (c0 == c1) ? 1 : 2;  // 1=pos, 2=neg
        flags[e] = f;
    }

    cg::this_grid().sync();   // device-scope barrier + fence (cooperative launch)
    if (blockIdx.x != 0) return;

    // ===== fused phase: block 0 only (1024 threads) =====
    s_pk[2 * tid] = 0; s_pk[2 * tid + 1] = 0;
    __syncthreads();

    // B0: reload per-edge anchor+flag (coalesced), packed counts
    const int2* ed2 = (const int2*)edges;
    uint32_t af[8];  // anchor(<<2) | flag
#pragma unroll
    for (int it = 0; it < 8; ++it) {
        int e = tid + it * NTHR;
        int a = ed2[e].x;
        int f = flags[e];
        af[it] = ((uint32_t)a << 2) | (uint32_t)f;
        if (f == 1)      atomicAdd(&s_pk[a], 1);
        else if (f == 2) atomicAdd(&s_pk[a], 0x10000);
    }
    __syncthreads();

    // B: pair counts, then in-place scans
    {
        int i0 = 2 * tid, i1 = i0 + 1;
        int p0 = s_pk[i0], p1 = s_pk[i1];
        s_q[i0] = (p0 & 0xFFFF) * (p0 >> 16);
        s_q[i1] = (p1 & 0xFFFF) * (p1 >> 16);
    }
    __syncthreads();
    scan_inplace(s_pk, s_tmp, &s_totPk);
    scan_inplace(s_q, s_tmp, &s_totQ);
    s_cur[2 * tid] = s_pk[2 * tid];
    s_cur[2 * tid + 1] = s_pk[2 * tid + 1];
    __syncthreads();
    int nPosTot = s_totPk & 0xFFFF;
    int nNegTot = s_totPk >> 16;
    int P = s_totQ; if (P > pmax) P = pmax;

    // C: CSR fill (packed cursors; pos in low16, neg in high16)
#pragma unroll
    for (int it = 0; it < 8; ++it) {
        int f = (int)(af[it] & 3u);
        int a = (int)(af[it] >> 2);
        int e = tid + it * NTHR;
        if (f == 1) {
            int old = atomicAdd(&s_cur[a], 1);
            s_csr[old & 0xFFFF] = (uint16_t)e;
        } else if (f == 2) {
            int old = atomicAdd(&s_cur[a], 0x10000);
            s_csr[nPosTot + (old >> 16)] = (uint16_t)e;
        }
    }
    __syncthreads();

    // D: one thread per valid pair; first RCAP pairs live in registers
    auto make_cand = [&](int t, float& val, uint32_t& pack) {
        int lo = 0, hi = N_CONST - 1;
#pragma unroll
        for (int itr = 0; itr < 11; ++itr) {  // largest a with s_q[a] <= t
            int mid = (lo + hi + 1) >> 1;
            if (s_q[mid] <= t) lo = mid; else hi = mid - 1;
        }
        int a = lo;
        int loc = t - s_q[a];
        int pk = s_pk[a];
        int pb = pk & 0xFFFF, nb = pk >> 16;
        int nextN = (a < N_CONST - 1) ? (s_pk[a + 1] >> 16) : nNegTot;
        int nn = nextN - nb;  // >= 1 for any anchor owning pairs
        int ip = loc / nn;
        int jn = loc - ip * nn;
        int i = s_csr[pb + ip];
        int j = s_csr[nPosTot + nb + jn];
        float w = 1.0f - 0.5f * (bc[i] + bc[j]);
        val = (w > 0.0f)
            ? logf(fmaxf(w, EPS_F)) + gumbel_at((uint32_t)i * E_CONST + (uint32_t)j)
            : -INFINITY;  // ref: logw=-inf -> excluded via ok mask
        pack = ((uint32_t)i << 16) | (uint32_t)j;
    };

    float vval0 = 0.f, vval1 = 0.f, vval2 = 0.f, vval3 = 0.f;      // static-indexed (rule #20)
    uint32_t vpk0 = 0, vpk1 = 0, vpk2 = 0, vpk3 = 0;
    if (tid          < P) make_cand(tid,          vval0, vpk0);
    if (tid + 1024   < P) make_cand(tid + 1024,   vval1, vpk1);
    if (tid + 2048   < P) make_cand(tid + 2048,   vval2, vpk2);
    if (tid + 3072   < P) make_cand(tid + 3072,   vval3, vpk3);
    for (int t = tid + RCAP; t < P; t += NTHR) {  // spill path (statistically unused)
        float v; uint32_t pk;
        make_cand(t, v, pk);
        spill[t - RCAP].val = v; spill[t - RCAP].pack = pk;
    }
    uint32_t vk0 = sortable_key(vval0), vk1 = sortable_key(vval1);
    uint32_t vk2 = sortable_key(vval2), vk3 = sortable_key(vval3);
    __syncthreads();

    // E: 4-pass radix threshold (wave-0 shfl suffix-scan bin select), keys from regs
    int M = P;
    uint32_t thr = 0;
    if (M > MAXS) {
        if (tid == 0) { s_prefix = 0; s_target = MAXS; }
        __syncthreads();
        for (int pass = 0; pass < 4; ++pass) {
            int shift = 24 - 8 * pass;
            if (tid < 256) s_hist[tid] = 0;
            __syncthreads();
            uint32_t pfx = s_prefix;
            if (tid          < M && (pass == 0 || (vk0 >> (shift + 8)) == pfx)) atomicAdd(&s_hist[(vk0 >> shift) & 255], 1);
            if (tid + 1024   < M && (pass == 0 || (vk1 >> (shift + 8)) == pfx)) atomicAdd(&s_hist[(vk1 >> shift) & 255], 1);
            if (tid + 2048   < M && (pass == 0 || (vk2 >> (shift + 8)) == pfx)) atomicAdd(&s_hist[(vk2 >> shift) & 255], 1);
            if (tid + 3072   < M && (pass == 0 || (vk3 >> (shift + 8)) == pfx)) atomicAdd(&s_hist[(vk3 >> shift) & 255], 1);
            for (int t = tid + RCAP; t < M; t += NTHR) {
                uint32_t k = sortable_key(spill[t - RCAP].val);
                if (pass == 0 || (k >> (shift + 8)) == pfx)
                    atomicAdd(&s_hist[(k >> shift) & 255], 1);
            }
            __syncthreads();
            if (tid < 64) {  // lane L owns bins 4L..4L+3
                int h0 = s_hist[4 * tid], h1 = s_hist[4 * tid + 1];
                int h2 = s_hist[4 * tid + 2], h3 = s_hist[4 * tid + 3];
                int sincl = h0 + h1 + h2 + h3;
#pragma unroll
                for (int off = 1; off < 64; off <<= 1) {
                    int v = __shfl_down(sincl, off);
                    if (tid + off < 64) sincl += v;
                }
                int excl = __shfl_down(sincl, 1);
                if (tid == 63) excl = 0;
                int suf3 = excl + h3;
                int suf2 = suf3 + h2;
                int suf1 = suf2 + h1;
                int suf0 = suf1 + h0;
                int tgt = s_target;
                uint32_t pfxOld = s_prefix;
                if      (suf0 >= tgt && suf1 < tgt) { s_prefix = (pfxOld << 8) | (4u*tid+0); s_target = tgt - suf1; }
                else if (suf1 >= tgt && suf2 < tgt) { s_prefix = (pfxOld << 8) | (4u*tid+1); s_target = tgt - suf2; }
                else if (suf2 >= tgt && suf3 < tgt) { s_prefix = (pfxOld << 8) | (4u*tid+2); s_target = tgt - suf3; }
                else if (suf3 >= tgt && excl < tgt) { s_prefix = (pfxOld << 8) | (4u*tid+3); s_target = tgt - excl; }
            }
            __syncthreads();
        }
        thr = s_prefix;  // exact sortable key of the 400th-largest value
    }

    // F: deterministic reduce of selected terms (regs + spill, fixed t order)
    float mysum = 0.f;
    int myc = 0;
    auto accum = [&](int t, float v, uint32_t k, uint32_t pk) {
        if (t < M && v != -INFINITY && k >= thr) {
            int i = (int)(pk >> 16), j = (int)(pk & 0xFFFFu);
            float pi = probas[i], pj = probas[j];
            mysum += logf(pi / (pi + pj));
            myc++;
        }
    };
    accum(tid,        vval0, vk0, vpk0);
    accum(tid + 1024, vval1, vk1, vpk1);
    accum(tid + 2048, vval2, vk2, vpk2);
    accum(tid + 3072, vval3, vk3, vpk3);
    for (int t = tid + RCAP; t < M; t += NTHR) {
        Cand c = spill[t - RCAP];
        accum(t, c.val, sortable_key(c.val), c.pack);
    }
#pragma unroll
    for (int off = 32; off > 0; off >>= 1) {
        mysum += __shfl_down(mysum, off);
        myc   += __shfl_down(myc, off);
    }
    int wid = tid >> 6;
    if ((tid & 63) == 0) { s_wsum[wid] = mysum; s_wcnt[wid] = myc; }
    __syncthreads();
    if (tid == 0) {
        float s = 0.f; int c = 0;
        for (int w = 0; w < 16; ++w) { s += s_wsum[w]; c += s_wcnt[w]; }
        if (c < 1) c = 1;
        out[0] = -s / (float)c;
    }
}

extern "C" void kernel_launch(void* const* d_in, const int* in_sizes, int n_in,
                              void* d_out, int out_size, void* d_ws, size_t ws_size,
                              hipStream_t stream) {
    const float* probas   = (const float*)d_in[0];
    const float* clusters = (const float*)d_in[1];
    const int*   edges    = (const int*)d_in[2];
    const int*   keypts   = (const int*)d_in[3];
    float* out = (float*)d_out;

    char* ws = (char*)d_ws;
    float*         bc    = (float*)(ws);                  // 32768 B
    unsigned char* flags = (unsigned char*)(ws + 32768);  // 8192 B
    Cand*          spill = (Cand*)(ws + 40960);           // overflow candidates
    long long avail = (long long)ws_size - 40960;
    int spill_cap = (avail > 0) ? (int)(avail / 8) : 0;
    if (spill_cap > 61440) spill_cap = 61440;
    int pmax = RCAP + spill_cap;

    void* args[] = {(void*)&probas, (void*)&clusters, (void*)&edges, (void*)&keypts,
                    (void*)&bc, (void*)&flags, (void*)&spill, (void*)&pmax, (void*)&out};
    hipLaunchCooperativeKernel((const void*)k_all, dim3(PREP_BLOCKS), dim3(NTHR),
                               args, 0, stream);
}

// Round 8
// 28.625 us; speedup vs baseline: 1.7310x; 1.7310x over previous
//
#include <hip/hip_runtime.h>
#include <stdint.h>

// TripletLoss on MI355X. E=8192, N=2048, K=8, L=16, top-400 of Gumbel-perturbed logw.
// Round 8: ONE plain dispatch, 1 block x 1024, 142KB dynamic LDS.
// Key move: clusters (64KB) is staged COALESCED into LDS once; per-node argmax
// computed once (2048 nodes). All per-edge / per-pair work then hits LDS, killing
// round 5's single-CU random-gather wall without round 7's grid-sync cost.
// bc computed lazily per pair from LDS rows (same float ops/order -> absmax 0.0).
// Candidates in 4 regs/thread (validated R7); radix threshold via wave-0 suffix scan.

#define E_CONST 8192
#define N_CONST 2048
#define K_CONST 8
#define L_CONST 16
#define MAXS 400
#define EPS_F 1e-9f
#define NTHR 1024
#define RCAP 4096  // register-resident candidates (4 per thread)

// ---- dynamic LDS layout (bytes) ----
#define OFF_CLUA   0        // float4[2048]  (k=0..3 per node)
#define OFF_CLUB   32768    // float4[2048]  (k=4..7 per node)
#define OFF_PK     65536    // int[2048]     packed cnt/base: P low16 | N high16
#define OFF_Q      73728    // int[2048]     pair cnt -> pair base
#define OFF_CUR    81920    // int[2048]     packed fill cursors
#define OFF_CSR    90112    // uint16[8192]  pos ids [0,nPosTot), neg after
#define OFF_EDGE   106496   // uint32[8192]  e0<<16 | e1
#define OFF_CLST   139264   // uint8[2048]   per-node argmax cluster
#define OFF_TMP    141312   // int[16]
#define OFF_HIST   141376   // int[256]
#define OFF_WSUM   142400   // float[16]
#define OFF_WCNT   142464   // int[16]
#define OFF_MISC   142528   // [0]=mask [1]=totPk [2]=totQ [3]=prefix [4]=target
#define LDS_BYTES  142592

struct Cand { float val; uint32_t pack; };

// ---- threefry2x32, key = jax.random.key(42), partitionable path (validated absmax 0.0) ----
__device__ __forceinline__ uint2 threefry2x32_42(uint32_t x0, uint32_t x1) {
    const uint32_t ks0 = 0u, ks1 = 42u;
    const uint32_t ks2 = ks0 ^ ks1 ^ 0x1BD11BDAu;
    const uint32_t ks[3] = {ks0, ks1, ks2};
    const int R[2][4] = {{13, 15, 26, 6}, {17, 29, 16, 24}};
    x0 += ks0; x1 += ks1;
#pragma unroll
    for (int g = 0; g < 5; ++g) {
        const int* r = R[g & 1];
#pragma unroll
        for (int q = 0; q < 4; ++q) {
            x0 += x1;
            x1 = (x1 << r[q]) | (x1 >> (32 - r[q]));
            x1 ^= x0;
        }
        x0 += ks[(g + 1) % 3];
        x1 += ks[(g + 2) % 3] + (uint32_t)(g + 1);
    }
    return make_uint2(x0, x1);
}

__device__ __forceinline__ float gumbel_at(uint32_t idx) {
    uint2 o = threefry2x32_42(0u, idx);
    uint32_t bits = o.x ^ o.y;
    float u = __uint_as_float((bits >> 9) | 0x3F800000u) - 1.0f;
    return -logf(-logf(u + EPS_F) + EPS_F);
}

__device__ __forceinline__ uint32_t sortable_key(float f) {
    uint32_t b = __float_as_uint(f);
    return (b & 0x80000000u) ? ~b : (b | 0x80000000u);
}

__device__ __forceinline__ int argmax8(float4 a, float4 b) {
    float v[8] = {a.x, a.y, a.z, a.w, b.x, b.y, b.z, b.w};
    float best = v[0]; int bi = 0;
#pragma unroll
    for (int k = 1; k < 8; ++k)
        if (v[k] > best) { best = v[k]; bi = k; }  // first-max == jnp.argmax
    return bi;
}

// exclusive in-place scan of arr[2048] by 1024 threads (each owns 2 elems).
// Works for 16|16 packed fields: per-field totals < 65536 -> no cross-field carry.
__device__ __forceinline__ void scan_inplace(int* arr, int* tmp, int* totalOut) {
    int tid = threadIdx.x;
    int lane = tid & 63, wid = tid >> 6;
    int i0 = 2 * tid, i1 = i0 + 1;
    int v0 = arr[i0], v1 = arr[i1];
    int s = v0 + v1;
    int inc = s;
#pragma unroll
    for (int off = 1; off < 64; off <<= 1) {
        int u = __shfl_up(inc, off);
        if (lane >= off) inc += u;
    }
    if (lane == 63) tmp[wid] = inc;
    __syncthreads();
    if (wid == 0) {
        int w = (lane < 16) ? tmp[lane] : 0;
        int incw = w;
#pragma unroll
        for (int off = 1; off < 16; off <<= 1) {
            int u = __shfl_up(incw, off);
            if (lane >= off) incw += u;
        }
        if (lane < 16) tmp[lane] = incw - w;  // exclusive wave bases
    }
    __syncthreads();
    int base = tmp[wid] + (inc - s);
    arr[i0] = base;
    arr[i1] = base + v0;
    if (tid == 1023) *totalOut = base + v0 + v1;
    __syncthreads();
}

__global__ __launch_bounds__(1024) void k_all(
    const float* __restrict__ probas, const float* __restrict__ clusters,
    const int* __restrict__ edges, const int* __restrict__ keypts,
    Cand* __restrict__ spill, int pmax, float* __restrict__ out) {

    extern __shared__ char smem[];
    float4*   s_cluA = (float4*)(smem + OFF_CLUA);
    float4*   s_cluB = (float4*)(smem + OFF_CLUB);
    int*      s_pk   = (int*)(smem + OFF_PK);
    int*      s_q    = (int*)(smem + OFF_Q);
    int*      s_cur  = (int*)(smem + OFF_CUR);
    uint16_t* s_csr  = (uint16_t*)(smem + OFF_CSR);
    uint32_t* s_edge = (uint32_t*)(smem + OFF_EDGE);
    uint8_t*  s_clst = (uint8_t*)(smem + OFF_CLST);
    int*      s_tmp  = (int*)(smem + OFF_TMP);
    int*      s_hist = (int*)(smem + OFF_HIST);
    float*    s_wsum = (float*)(smem + OFF_WSUM);
    int*      s_wcnt = (int*)(smem + OFF_WCNT);
    int*      s_misc = (int*)(smem + OFF_MISC);

    int tid = threadIdx.x;
    s_pk[tid] = 0; s_pk[tid + 1024] = 0;
    if (tid == 0) s_misc[0] = 0;

    // ===== A1: stage clusters coalesced into LDS + per-node argmax =====
    const float4* c4 = (const float4*)clusters;
#pragma unroll
    for (int r = 0; r < 2; ++r) {
        int n = tid + r * 1024;
        float4 a = c4[2 * n], b = c4[2 * n + 1];
        s_cluA[n] = a; s_cluB[n] = b;
        s_clst[n] = (uint8_t)argmax8(a, b);
    }
    __syncthreads();
    if (tid < L_CONST)
        atomicOr((uint32_t*)&s_misc[0], 1u << s_clst[keypts[tid]]);
    __syncthreads();
    uint32_t m = (uint32_t)s_misc[0];

    // ===== A2: per-edge flags + packed counts (edges coalesced, clst from LDS) =====
    const int2* ed2 = (const int2*)edges;
    uint32_t af[8];  // anchor(<<2) | flag
#pragma unroll
    for (int it = 0; it < 8; ++it) {
        int e = tid + it * NTHR;
        int2 p = ed2[e];
        s_edge[e] = ((uint32_t)p.x << 16) | (uint32_t)p.y;
        int c0 = s_clst[p.x], c1 = s_clst[p.y];
        int f = 0;
        if ((((m >> c0) | (m >> c1)) & 1u)) f = (c0 == c1) ? 1 : 2;  // 1=pos, 2=neg
        af[it] = ((uint32_t)p.x << 2) | (uint32_t)f;
        if (f == 1)      atomicAdd(&s_pk[p.x], 1);
        else if (f == 2) atomicAdd(&s_pk[p.x], 0x10000);
    }
    __syncthreads();

    // ===== B: pair counts + in-place scans =====
    {
        int i0 = 2 * tid, i1 = i0 + 1;
        int p0 = s_pk[i0], p1 = s_pk[i1];
        s_q[i0] = (p0 & 0xFFFF) * (p0 >> 16);
        s_q[i1] = (p1 & 0xFFFF) * (p1 >> 16);
    }
    __syncthreads();
    scan_inplace(s_pk, s_tmp, &s_misc[1]);
    scan_inplace(s_q, s_tmp, &s_misc[2]);
    s_cur[2 * tid] = s_pk[2 * tid];
    s_cur[2 * tid + 1] = s_pk[2 * tid + 1];
    __syncthreads();
    int nPosTot = s_misc[1] & 0xFFFF;
    int nNegTot = s_misc[1] >> 16;
    int P = s_misc[2]; if (P > pmax) P = pmax;

    // ===== C: CSR fill (packed cursors; pos low16, neg high16) =====
#pragma unroll
    for (int it = 0; it < 8; ++it) {
        int f = (int)(af[it] & 3u);
        int a = (int)(af[it] >> 2);
        int e = tid + it * NTHR;
        if (f == 1) {
            int old = atomicAdd(&s_cur[a], 1);
            s_csr[old & 0xFFFF] = (uint16_t)e;
        } else if (f == 2) {
            int old = atomicAdd(&s_cur[a], 0x10000);
            s_csr[nPosTot + (old >> 16)] = (uint16_t)e;
        }
    }
    __syncthreads();

    // ===== D: one thread per valid pair; lazy bc from LDS rows; cands in regs =====
    auto bc_of = [&](int e) -> float {
        uint32_t pe = s_edge[e];
        int n0 = (int)(pe >> 16), n1 = (int)(pe & 0xFFFFu);
        float4 a0 = s_cluA[n0], a1 = s_cluB[n0];
        float4 b0 = s_cluA[n1], b1 = s_cluB[n1];
        float s = sqrtf(a0.x * b0.x);       // k ascending, matches ref reduce order
        s += sqrtf(a0.y * b0.y);
        s += sqrtf(a0.z * b0.z);
        s += sqrtf(a0.w * b0.w);
        s += sqrtf(a1.x * b1.x);
        s += sqrtf(a1.y * b1.y);
        s += sqrtf(a1.z * b1.z);
        s += sqrtf(a1.w * b1.w);
        return s;
    };
    auto make_cand = [&](int t, float& val, uint32_t& pack) {
        int lo = 0, hi = N_CONST - 1;
#pragma unroll
        for (int itr = 0; itr < 11; ++itr) {  // largest a with s_q[a] <= t
            int mid = (lo + hi + 1) >> 1;
            if (s_q[mid] <= t) lo = mid; else hi = mid - 1;
        }
        int a = lo;
        int loc = t - s_q[a];
        int pk = s_pk[a];
        int pb = pk & 0xFFFF, nb = pk >> 16;
        int nextN = (a < N_CONST - 1) ? (s_pk[a + 1] >> 16) : nNegTot;
        int nn = nextN - nb;  // >= 1 for any anchor owning pairs
        int ip = loc / nn;
        int jn = loc - ip * nn;
        int i = s_csr[pb + ip];
        int j = s_csr[nPosTot + nb + jn];
        float w = 1.0f - 0.5f * (bc_of(i) + bc_of(j));
        val = (w > 0.0f)
            ? logf(fmaxf(w, EPS_F)) + gumbel_at((uint32_t)i * E_CONST + (uint32_t)j)
            : -INFINITY;  // ref: logw=-inf -> excluded via ok mask
        pack = ((uint32_t)i << 16) | (uint32_t)j;
    };

    float vval0 = 0.f, vval1 = 0.f, vval2 = 0.f, vval3 = 0.f;  // static-indexed (rule #20)
    uint32_t vpk0 = 0, vpk1 = 0, vpk2 = 0, vpk3 = 0;
    if (tid        < P) make_cand(tid,        vval0, vpk0);
    if (tid + 1024 < P) make_cand(tid + 1024, vval1, vpk1);
    if (tid + 2048 < P) make_cand(tid + 2048, vval2, vpk2);
    if (tid + 3072 < P) make_cand(tid + 3072, vval3, vpk3);
    for (int t = tid + RCAP; t < P; t += NTHR) {  // spill path (statistically unused)
        float v; uint32_t pk;
        make_cand(t, v, pk);
        spill[t - RCAP].val = v; spill[t - RCAP].pack = pk;
    }
    uint32_t vk0 = sortable_key(vval0), vk1 = sortable_key(vval1);
    uint32_t vk2 = sortable_key(vval2), vk3 = sortable_key(vval3);
    __syncthreads();

    // ===== E: 4-pass radix threshold (wave-0 shfl suffix-scan bin select) =====
    uint32_t* s_prefix = (uint32_t*)&s_misc[3];
    int*      s_target = &s_misc[4];
    int M = P;
    uint32_t thr = 0;
    if (M > MAXS) {
        if (tid == 0) { *s_prefix = 0; *s_target = MAXS; }
        __syncthreads();
        for (int pass = 0; pass < 4; ++pass) {
            int shift = 24 - 8 * pass;
            if (tid < 256) s_hist[tid] = 0;
            __syncthreads();
            uint32_t pfx = *s_prefix;
            if (tid        < M && (pass == 0 || (vk0 >> (shift + 8)) == pfx)) atomicAdd(&s_hist[(vk0 >> shift) & 255], 1);
            if (tid + 1024 < M && (pass == 0 || (vk1 >> (shift + 8)) == pfx)) atomicAdd(&s_hist[(vk1 >> shift) & 255], 1);
            if (tid + 2048 < M && (pass == 0 || (vk2 >> (shift + 8)) == pfx)) atomicAdd(&s_hist[(vk2 >> shift) & 255], 1);
            if (tid + 3072 < M && (pass == 0 || (vk3 >> (shift + 8)) == pfx)) atomicAdd(&s_hist[(vk3 >> shift) & 255], 1);
            for (int t = tid + RCAP; t < M; t += NTHR) {
                uint32_t k = sortable_key(spill[t - RCAP].val);
                if (pass == 0 || (k >> (shift + 8)) == pfx)
                    atomicAdd(&s_hist[(k >> shift) & 255], 1);
            }
            __syncthreads();
            if (tid < 64) {  // lane L owns bins 4L..4L+3
                int h0 = s_hist[4 * tid], h1 = s_hist[4 * tid + 1];
                int h2 = s_hist[4 * tid + 2], h3 = s_hist[4 * tid + 3];
                int sincl = h0 + h1 + h2 + h3;
#pragma unroll
                for (int off = 1; off < 64; off <<= 1) {
                    int v = __shfl_down(sincl, off);
                    if (tid + off < 64) sincl += v;
                }
                int excl = __shfl_down(sincl, 1);
                if (tid == 63) excl = 0;
                int suf3 = excl + h3;
                int suf2 = suf3 + h2;
                int suf1 = suf2 + h1;
                int suf0 = suf1 + h0;
                int tgt = *s_target;
                uint32_t pfxOld = *s_prefix;
                if      (suf0 >= tgt && suf1 < tgt) { *s_prefix = (pfxOld << 8) | (4u*tid+0); *s_target = tgt - suf1; }
                else if (suf1 >= tgt && suf2 < tgt) { *s_prefix = (pfxOld << 8) | (4u*tid+1); *s_target = tgt - suf2; }
                else if (suf2 >= tgt && suf3 < tgt) { *s_prefix = (pfxOld << 8) | (4u*tid+2); *s_target = tgt - suf3; }
                else if (suf3 >= tgt && excl < tgt) { *s_prefix = (pfxOld << 8) | (4u*tid+3); *s_target = tgt - excl; }
            }
            __syncthreads();
        }
        thr = *s_prefix;  // exact sortable key of the 400th-largest value
    }

    // ===== F: deterministic reduce of selected terms =====
    float mysum = 0.f;
    int myc = 0;
    auto accum = [&](int t, float v, uint32_t k, uint32_t pk) {
        if (t < M && v != -INFINITY && k >= thr) {
            int i = (int)(pk >> 16), j = (int)(pk & 0xFFFFu);
            float pi = probas[i], pj = probas[j];
            mysum += logf(pi / (pi + pj));
            myc++;
        }
    };
    accum(tid,        vval0, vk0, vpk0);
    accum(tid + 1024, vval1, vk1, vpk1);
    accum(tid + 2048, vval2, vk2, vpk2);
    accum(tid + 3072, vval3, vk3, vpk3);
    for (int t = tid + RCAP; t < M; t += NTHR) {
        Cand c = spill[t - RCAP];
        accum(t, c.val, sortable_key(c.val), c.pack);
    }
#pragma unroll
    for (int off = 32; off > 0; off >>= 1) {
        mysum += __shfl_down(mysum, off);
        myc   += __shfl_down(myc, off);
    }
    int wid = tid >> 6;
    if ((tid & 63) == 0) { s_wsum[wid] = mysum; s_wcnt[wid] = myc; }
    __syncthreads();
    if (tid == 0) {
        float s = 0.f; int c = 0;
        for (int w = 0; w < 16; ++w) { s += s_wsum[w]; c += s_wcnt[w]; }
        if (c < 1) c = 1;
        out[0] = -s / (float)c;
    }
}

extern "C" void kernel_launch(void* const* d_in, const int* in_sizes, int n_in,
                              void* d_out, int out_size, void* d_ws, size_t ws_size,
                              hipStream_t stream) {
    const float* probas   = (const float*)d_in[0];
    const float* clusters = (const float*)d_in[1];
    const int*   edges    = (const int*)d_in[2];
    const int*   keypts   = (const int*)d_in[3];
    float* out = (float*)d_out;

    Cand* spill = (Cand*)d_ws;
    int spill_cap = (int)(ws_size / sizeof(Cand));
    if (spill_cap > 61440) spill_cap = 61440;
    int pmax = RCAP + spill_cap;

    // allow >64KB dynamic LDS (idempotent host-side call; not a stream op)
    hipFuncSetAttribute((const void*)k_all,
                        hipFuncAttributeMaxDynamicSharedMemorySize, LDS_BYTES);

    k_all<<<1, NTHR, LDS_BYTES, stream>>>(probas, clusters, edges, keypts,
                                          spill, pmax, out);
}

// Round 9
// 27.998 us; speedup vs baseline: 1.7698x; 1.0224x over previous
//
#include <hip/hip_runtime.h>
#include <stdint.h>

// TripletLoss on MI355X. E=8192, N=2048, K=8, L=16, top-400 of Gumbel-perturbed logw.
// Round 9: single 1-block dispatch (R8 structure) + three single-CU optimizations:
//  - native v_log_f32 / v_sqrt_f32 (__logf / __builtin_amdgcn_sqrtf): bc & ranking
//    only choose WHICH pairs win; output term error ~1e-6 << 1.7e-2 threshold.
//  - ballot-aggregated LDS histogram atomics (pass-0 bins cluster in ~6 exponent
//    buckets -> same-address atomic serialization was ~5us; now 1 atomic/group/wave).
//  - edge-table register preload overlapping cluster LDS staging.

#define E_CONST 8192
#define N_CONST 2048
#define K_CONST 8
#define L_CONST 16
#define MAXS 400
#define EPS_F 1e-9f
#define NTHR 1024
#define RCAP 4096  // register-resident candidates (4 per thread)

// ---- dynamic LDS layout (bytes) ----
#define OFF_CLUA   0        // float4[2048]  (k=0..3 per node)
#define OFF_CLUB   32768    // float4[2048]  (k=4..7 per node)
#define OFF_PK     65536    // int[2048]     packed cnt/base: P low16 | N high16
#define OFF_Q      73728    // int[2048]     pair cnt -> pair base
#define OFF_CUR    81920    // int[2048]     packed fill cursors
#define OFF_CSR    90112    // uint16[8192]  pos ids [0,nPosTot), neg after
#define OFF_EDGE   106496   // uint32[8192]  e0<<16 | e1
#define OFF_CLST   139264   // uint8[2048]   per-node argmax cluster
#define OFF_TMP    141312   // int[16]
#define OFF_HIST   141376   // int[256]
#define OFF_WSUM   142400   // float[16]
#define OFF_WCNT   142464   // int[16]
#define OFF_MISC   142528   // [0]=mask [1]=totPk [2]=totQ [3]=prefix [4]=target
#define LDS_BYTES  142592

struct Cand { float val; uint32_t pack; };

// ---- threefry2x32, key = jax.random.key(42), partitionable path (validated absmax 0.0) ----
__device__ __forceinline__ uint2 threefry2x32_42(uint32_t x0, uint32_t x1) {
    const uint32_t ks0 = 0u, ks1 = 42u;
    const uint32_t ks2 = ks0 ^ ks1 ^ 0x1BD11BDAu;
    const uint32_t ks[3] = {ks0, ks1, ks2};
    const int R[2][4] = {{13, 15, 26, 6}, {17, 29, 16, 24}};
    x0 += ks0; x1 += ks1;
#pragma unroll
    for (int g = 0; g < 5; ++g) {
        const int* r = R[g & 1];
#pragma unroll
        for (int q = 0; q < 4; ++q) {
            x0 += x1;
            x1 = (x1 << r[q]) | (x1 >> (32 - r[q]));
            x1 ^= x0;
        }
        x0 += ks[(g + 1) % 3];
        x1 += ks[(g + 2) % 3] + (uint32_t)(g + 1);
    }
    return make_uint2(x0, x1);
}

__device__ __forceinline__ float gumbel_at(uint32_t idx) {
    uint2 o = threefry2x32_42(0u, idx);
    uint32_t bits = o.x ^ o.y;
    float u = __uint_as_float((bits >> 9) | 0x3F800000u) - 1.0f;
    return -__logf(-__logf(u + EPS_F) + EPS_F);  // ranking-only: native log ok
}

__device__ __forceinline__ uint32_t sortable_key(float f) {
    uint32_t b = __float_as_uint(f);
    return (b & 0x80000000u) ? ~b : (b | 0x80000000u);
}

__device__ __forceinline__ int argmax8(float4 a, float4 b) {
    float v[8] = {a.x, a.y, a.z, a.w, b.x, b.y, b.z, b.w};
    float best = v[0]; int bi = 0;
#pragma unroll
    for (int k = 1; k < 8; ++k)
        if (v[k] > best) { best = v[k]; bi = k; }  // first-max == jnp.argmax
    return bi;
}

// exclusive in-place scan of arr[2048] by 1024 threads (each owns 2 elems).
// Works for 16|16 packed fields: per-field totals < 65536 -> no cross-field carry.
__device__ __forceinline__ void scan_inplace(int* arr, int* tmp, int* totalOut) {
    int tid = threadIdx.x;
    int lane = tid & 63, wid = tid >> 6;
    int i0 = 2 * tid, i1 = i0 + 1;
    int v0 = arr[i0], v1 = arr[i1];
    int s = v0 + v1;
    int inc = s;
#pragma unroll
    for (int off = 1; off < 64; off <<= 1) {
        int u = __shfl_up(inc, off);
        if (lane >= off) inc += u;
    }
    if (lane == 63) tmp[wid] = inc;
    __syncthreads();
    if (wid == 0) {
        int w = (lane < 16) ? tmp[lane] : 0;
        int incw = w;
#pragma unroll
        for (int off = 1; off < 16; off <<= 1) {
            int u = __shfl_up(incw, off);
            if (lane >= off) incw += u;
        }
        if (lane < 16) tmp[lane] = incw - w;  // exclusive wave bases
    }
    __syncthreads();
    int base = tmp[wid] + (inc - s);
    arr[i0] = base;
    arr[i1] = base + v0;
    if (tid == 1023) *totalOut = base + v0 + v1;
    __syncthreads();
}

__global__ __launch_bounds__(1024) void k_all(
    const float* __restrict__ probas, const float* __restrict__ clusters,
    const int* __restrict__ edges, const int* __restrict__ keypts,
    Cand* __restrict__ spill, int pmax, float* __restrict__ out) {

    extern __shared__ char smem[];
    float4*   s_cluA = (float4*)(smem + OFF_CLUA);
    float4*   s_cluB = (float4*)(smem + OFF_CLUB);
    int*      s_pk   = (int*)(smem + OFF_PK);
    int*      s_q    = (int*)(smem + OFF_Q);
    int*      s_cur  = (int*)(smem + OFF_CUR);
    uint16_t* s_csr  = (uint16_t*)(smem + OFF_CSR);
    uint32_t* s_edge = (uint32_t*)(smem + OFF_EDGE);
    uint8_t*  s_clst = (uint8_t*)(smem + OFF_CLST);
    int*      s_tmp  = (int*)(smem + OFF_TMP);
    int*      s_hist = (int*)(smem + OFF_HIST);
    float*    s_wsum = (float*)(smem + OFF_WSUM);
    int*      s_wcnt = (int*)(smem + OFF_WCNT);
    int*      s_misc = (int*)(smem + OFF_MISC);

    int tid = threadIdx.x;
    int lane = tid & 63;

    // preload edge table into regs (overlaps with cluster staging latency)
    const int2* ed2 = (const int2*)edges;
    int2 pre[8];
#pragma unroll
    for (int it = 0; it < 8; ++it) pre[it] = ed2[tid + it * NTHR];

    s_pk[tid] = 0; s_pk[tid + 1024] = 0;
    if (tid == 0) s_misc[0] = 0;

    // ===== A1: stage clusters coalesced into LDS + per-node argmax =====
    const float4* c4 = (const float4*)clusters;
#pragma unroll
    for (int r = 0; r < 2; ++r) {
        int n = tid + r * 1024;
        float4 a = c4[2 * n], b = c4[2 * n + 1];
        s_cluA[n] = a; s_cluB[n] = b;
        s_clst[n] = (uint8_t)argmax8(a, b);
    }
    __syncthreads();
    if (tid < L_CONST)
        atomicOr((uint32_t*)&s_misc[0], 1u << s_clst[keypts[tid]]);
    __syncthreads();
    uint32_t m = (uint32_t)s_misc[0];

    // ===== A2: per-edge flags + packed counts (edges from regs, clst from LDS) =====
    uint32_t af[8];  // anchor(<<2) | flag
#pragma unroll
    for (int it = 0; it < 8; ++it) {
        int e = tid + it * NTHR;
        int2 p = pre[it];
        s_edge[e] = ((uint32_t)p.x << 16) | (uint32_t)p.y;
        int c0 = s_clst[p.x], c1 = s_clst[p.y];
        int f = 0;
        if ((((m >> c0) | (m >> c1)) & 1u)) f = (c0 == c1) ? 1 : 2;  // 1=pos, 2=neg
        af[it] = ((uint32_t)p.x << 2) | (uint32_t)f;
        if (f == 1)      atomicAdd(&s_pk[p.x], 1);
        else if (f == 2) atomicAdd(&s_pk[p.x], 0x10000);
    }
    __syncthreads();

    // ===== B: pair counts + in-place scans =====
    {
        int i0 = 2 * tid, i1 = i0 + 1;
        int p0 = s_pk[i0], p1 = s_pk[i1];
        s_q[i0] = (p0 & 0xFFFF) * (p0 >> 16);
        s_q[i1] = (p1 & 0xFFFF) * (p1 >> 16);
    }
    __syncthreads();
    scan_inplace(s_pk, s_tmp, &s_misc[1]);
    scan_inplace(s_q, s_tmp, &s_misc[2]);
    s_cur[2 * tid] = s_pk[2 * tid];
    s_cur[2 * tid + 1] = s_pk[2 * tid + 1];
    __syncthreads();
    int nPosTot = s_misc[1] & 0xFFFF;
    int nNegTot = s_misc[1] >> 16;
    int P = s_misc[2]; if (P > pmax) P = pmax;

    // ===== C: CSR fill (packed cursors; pos low16, neg high16) =====
#pragma unroll
    for (int it = 0; it < 8; ++it) {
        int f = (int)(af[it] & 3u);
        int a = (int)(af[it] >> 2);
        int e = tid + it * NTHR;
        if (f == 1) {
            int old = atomicAdd(&s_cur[a], 1);
            s_csr[old & 0xFFFF] = (uint16_t)e;
        } else if (f == 2) {
            int old = atomicAdd(&s_cur[a], 0x10000);
            s_csr[nPosTot + (old >> 16)] = (uint16_t)e;
        }
    }
    __syncthreads();

    // ===== D: one thread per valid pair; lazy bc from LDS rows; cands in regs =====
    auto bc_of = [&](int e) -> float {
        uint32_t pe = s_edge[e];
        int n0 = (int)(pe >> 16), n1 = (int)(pe & 0xFFFFu);
        float4 a0 = s_cluA[n0], a1 = s_cluB[n0];
        float4 b0 = s_cluA[n1], b1 = s_cluB[n1];
        float s = __builtin_amdgcn_sqrtf(a0.x * b0.x);  // ranking-only: native sqrt ok
        s += __builtin_amdgcn_sqrtf(a0.y * b0.y);
        s += __builtin_amdgcn_sqrtf(a0.z * b0.z);
        s += __builtin_amdgcn_sqrtf(a0.w * b0.w);
        s += __builtin_amdgcn_sqrtf(a1.x * b1.x);
        s += __builtin_amdgcn_sqrtf(a1.y * b1.y);
        s += __builtin_amdgcn_sqrtf(a1.z * b1.z);
        s += __builtin_amdgcn_sqrtf(a1.w * b1.w);
        return s;
    };
    auto make_cand = [&](int t, float& val, uint32_t& pack) {
        int lo = 0, hi = N_CONST - 1;
#pragma unroll
        for (int itr = 0; itr < 11; ++itr) {  // largest a with s_q[a] <= t
            int mid = (lo + hi + 1) >> 1;
            if (s_q[mid] <= t) lo = mid; else hi = mid - 1;
        }
        int a = lo;
        int loc = t - s_q[a];
        int pk = s_pk[a];
        int pb = pk & 0xFFFF, nb = pk >> 16;
        int nextN = (a < N_CONST - 1) ? (s_pk[a + 1] >> 16) : nNegTot;
        int nn = nextN - nb;  // >= 1 for any anchor owning pairs
        int ip = loc / nn;
        int jn = loc - ip * nn;
        int i = s_csr[pb + ip];
        int j = s_csr[nPosTot + nb + jn];
        float w = 1.0f - 0.5f * (bc_of(i) + bc_of(j));
        val = (w > 0.0f)
            ? __logf(fmaxf(w, EPS_F)) + gumbel_at((uint32_t)i * E_CONST + (uint32_t)j)
            : -INFINITY;  // ref: logw=-inf -> excluded via ok mask
        pack = ((uint32_t)i << 16) | (uint32_t)j;
    };

    float vval0 = 0.f, vval1 = 0.f, vval2 = 0.f, vval3 = 0.f;  // static-indexed (rule #20)
    uint32_t vpk0 = 0, vpk1 = 0, vpk2 = 0, vpk3 = 0;
    if (tid        < P) make_cand(tid,        vval0, vpk0);
    if (tid + 1024 < P) make_cand(tid + 1024, vval1, vpk1);
    if (tid + 2048 < P) make_cand(tid + 2048, vval2, vpk2);
    if (tid + 3072 < P) make_cand(tid + 3072, vval3, vpk3);
    for (int t = tid + RCAP; t < P; t += NTHR) {  // spill path (statistically unused)
        float v; uint32_t pk;
        make_cand(t, v, pk);
        spill[t - RCAP].val = v; spill[t - RCAP].pack = pk;
    }
    uint32_t vk0 = sortable_key(vval0), vk1 = sortable_key(vval1);
    uint32_t vk2 = sortable_key(vval2), vk3 = sortable_key(vval3);
    __syncthreads();

    // ===== E: 4-pass radix threshold; ballot-aggregated hist atomics =====
    uint32_t* s_prefix = (uint32_t*)&s_misc[3];
    int*      s_target = &s_misc[4];
    int M = P;
    uint32_t thr = 0;
    if (M > MAXS) {
        if (tid == 0) { *s_prefix = 0; *s_target = MAXS; }
        __syncthreads();
        for (int pass = 0; pass < 4; ++pass) {
            int shift = 24 - 8 * pass;
            if (tid < 256) s_hist[tid] = 0;
            __syncthreads();
            uint32_t pfx = *s_prefix;
            // wave-aggregated histogram add: group same-bin lanes via 9 ballots,
            // leader does one atomicAdd(bin, count). Kills same-address serialization.
            auto hist_add = [&](bool inRange, uint32_t k) {
                bool act = inRange && (pass == 0 || (k >> (shift + 8)) == pfx);
                uint32_t b = (k >> shift) & 255u;
                uint32_t v = act ? b : 256u;  // 9-bit match value; 256 = inactive group
                uint64_t peers = ~0ull;
#pragma unroll
                for (int bit = 0; bit < 9; ++bit) {
                    uint64_t vote = __ballot((v >> bit) & 1u);
                    peers &= ((v >> bit) & 1u) ? vote : ~vote;
                }
                if (act) {
                    int leader = __ffsll((unsigned long long)peers) - 1;
                    if (lane == leader) atomicAdd(&s_hist[b], (int)__popcll(peers));
                }
            };
            hist_add(tid        < M, vk0);
            hist_add(tid + 1024 < M, vk1);
            hist_add(tid + 2048 < M, vk2);
            hist_add(tid + 3072 < M, vk3);
            for (int t = tid + RCAP; t < M; t += NTHR) {
                uint32_t k = sortable_key(spill[t - RCAP].val);
                if (pass == 0 || (k >> (shift + 8)) == pfx)
                    atomicAdd(&s_hist[(k >> shift) & 255], 1);
            }
            __syncthreads();
            if (tid < 64) {  // wave 0: lane L owns bins 4L..4L+3, suffix-scan select
                int h0 = s_hist[4 * tid], h1 = s_hist[4 * tid + 1];
                int h2 = s_hist[4 * tid + 2], h3 = s_hist[4 * tid + 3];
                int sincl = h0 + h1 + h2 + h3;
#pragma unroll
                for (int off = 1; off < 64; off <<= 1) {
                    int v = __shfl_down(sincl, off);
                    if (tid + off < 64) sincl += v;
                }
                int excl = __shfl_down(sincl, 1);
                if (tid == 63) excl = 0;
                int suf3 = excl + h3;
                int suf2 = suf3 + h2;
                int suf1 = suf2 + h1;
                int suf0 = suf1 + h0;
                int tgt = *s_target;
                uint32_t pfxOld = *s_prefix;
                if      (suf0 >= tgt && suf1 < tgt) { *s_prefix = (pfxOld << 8) | (4u*tid+0); *s_target = tgt - suf1; }
                else if (suf1 >= tgt && suf2 < tgt) { *s_prefix = (pfxOld << 8) | (4u*tid+1); *s_target = tgt - suf2; }
                else if (suf2 >= tgt && suf3 < tgt) { *s_prefix = (pfxOld << 8) | (4u*tid+2); *s_target = tgt - suf3; }
                else if (suf3 >= tgt && excl < tgt) { *s_prefix = (pfxOld << 8) | (4u*tid+3); *s_target = tgt - excl; }
            }
            __syncthreads();
        }
        thr = *s_prefix;  // exact sortable key of the 400th-largest value
    }

    // ===== F: deterministic reduce of selected terms =====
    float mysum = 0.f;
    int myc = 0;
    auto accum = [&](int t, float v, uint32_t k, uint32_t pk) {
        if (t < M && v != -INFINITY && k >= thr) {
            int i = (int)(pk >> 16), j = (int)(pk & 0xFFFFu);
            float pi = probas[i], pj = probas[j];
            mysum += __logf(pi / (pi + pj));  // ~1e-6 abs err, threshold 1.7e-2
            myc++;
        }
    };
    accum(tid,        vval0, vk0, vpk0);
    accum(tid + 1024, vval1, vk1, vpk1);
    accum(tid + 2048, vval2, vk2, vpk2);
    accum(tid + 3072, vval3, vk3, vpk3);
    for (int t = tid + RCAP; t < M; t += NTHR) {
        Cand c = spill[t - RCAP];
        accum(t, c.val, sortable_key(c.val), c.pack);
    }
#pragma unroll
    for (int off = 32; off > 0; off >>= 1) {
        mysum += __shfl_down(mysum, off);
        myc   += __shfl_down(myc, off);
    }
    int wid = tid >> 6;
    if ((tid & 63) == 0) { s_wsum[wid] = mysum; s_wcnt[wid] = myc; }
    __syncthreads();
    if (tid == 0) {
        float s = 0.f; int c = 0;
        for (int w = 0; w < 16; ++w) { s += s_wsum[w]; c += s_wcnt[w]; }
        if (c < 1) c = 1;
        out[0] = -s / (float)c;
    }
}

extern "C" void kernel_launch(void* const* d_in, const int* in_sizes, int n_in,
                              void* d_out, int out_size, void* d_ws, size_t ws_size,
                              hipStream_t stream) {
    const float* probas   = (const float*)d_in[0];
    const float* clusters = (const float*)d_in[1];
    const int*   edges    = (const int*)d_in[2];
    const int*   keypts   = (const int*)d_in[3];
    float* out = (float*)d_out;

    Cand* spill = (Cand*)d_ws;
    int spill_cap = (int)(ws_size / sizeof(Cand));
    if (spill_cap > 61440) spill_cap = 61440;
    int pmax = RCAP + spill_cap;

    // allow >64KB dynamic LDS (idempotent host-side call; not a stream op)
    hipFuncSetAttribute((const void*)k_all,
                        hipFuncAttributeMaxDynamicSharedMemorySize, LDS_BYTES);

    k_all<<<1, NTHR, LDS_BYTES, stream>>>(probas, clusters, edges, keypts,
                                          spill, pmax, out);
}

// Round 10
// 26.220 us; speedup vs baseline: 1.8897x; 1.0678x over previous
//
#include <hip/hip_runtime.h>
#include <stdint.h>

// TripletLoss on MI355X. E=8192, N=2048, K=8, L=16, top-400 of Gumbel-perturbed logw.
// Round 10: single 1-block dispatch (R8/R9 structure), LDS-pipe diet:
//  - bc precomputed per EDGE in A2 (clusters LDS-resident) -> s_bc replaces s_edge;
//    phase D loses its 8x b128 cluster reads per candidate.
//  - pairAnchor table (u16[6144]) kills D's 11-dependent-read binary search.
//  - plain LDS-atomic histogram (R9 ballot version was a null -> revert, less VALU).

#define E_CONST 8192
#define N_CONST 2048
#define K_CONST 8
#define L_CONST 16
#define MAXS 400
#define EPS_F 1e-9f
#define NTHR 1024
#define RCAP 4096   // register-resident candidates (4 per thread)
#define TCAP 6144   // pairAnchor table capacity

// ---- dynamic LDS layout (bytes) ----
#define OFF_CLUA   0        // float4[2048]  (k=0..3 per node)
#define OFF_CLUB   32768    // float4[2048]  (k=4..7 per node)
#define OFF_PK     65536    // int[2048]     packed cnt/base: P low16 | N high16
#define OFF_Q      73728    // int[2048]     pair cnt -> pair base
#define OFF_CUR    81920    // int[2048]     packed fill cursors
#define OFF_CSR    90112    // uint16[8192]  pos ids [0,nPosTot), neg after
#define OFF_BC     106496   // float[8192]   per-edge Bhattacharyya coeff
#define OFF_CLST   139264   // uint8[2048]   per-node argmax cluster
#define OFF_PA     141312   // uint16[6144]  pair -> anchor
#define OFF_TMP    153600   // int[16]
#define OFF_HIST   153664   // int[256]
#define OFF_WSUM   154688   // float[16]
#define OFF_WCNT   154752   // int[16]
#define OFF_MISC   154816   // [0]=mask [1]=totPk [2]=totQ [3]=prefix [4]=target
#define LDS_BYTES  154848

struct Cand { float val; uint32_t pack; };

// ---- threefry2x32, key = jax.random.key(42), partitionable path (validated absmax 0.0) ----
__device__ __forceinline__ uint2 threefry2x32_42(uint32_t x0, uint32_t x1) {
    const uint32_t ks0 = 0u, ks1 = 42u;
    const uint32_t ks2 = ks0 ^ ks1 ^ 0x1BD11BDAu;
    const uint32_t ks[3] = {ks0, ks1, ks2};
    const int R[2][4] = {{13, 15, 26, 6}, {17, 29, 16, 24}};
    x0 += ks0; x1 += ks1;
#pragma unroll
    for (int g = 0; g < 5; ++g) {
        const int* r = R[g & 1];
#pragma unroll
        for (int q = 0; q < 4; ++q) {
            x0 += x1;
            x1 = (x1 << r[q]) | (x1 >> (32 - r[q]));
            x1 ^= x0;
        }
        x0 += ks[(g + 1) % 3];
        x1 += ks[(g + 2) % 3] + (uint32_t)(g + 1);
    }
    return make_uint2(x0, x1);
}

__device__ __forceinline__ float gumbel_at(uint32_t idx) {
    uint2 o = threefry2x32_42(0u, idx);
    uint32_t bits = o.x ^ o.y;
    float u = __uint_as_float((bits >> 9) | 0x3F800000u) - 1.0f;
    return -__logf(-__logf(u + EPS_F) + EPS_F);  // ranking-only: native log ok
}

__device__ __forceinline__ uint32_t sortable_key(float f) {
    uint32_t b = __float_as_uint(f);
    return (b & 0x80000000u) ? ~b : (b | 0x80000000u);
}

__device__ __forceinline__ int argmax8(float4 a, float4 b) {
    float v[8] = {a.x, a.y, a.z, a.w, b.x, b.y, b.z, b.w};
    float best = v[0]; int bi = 0;
#pragma unroll
    for (int k = 1; k < 8; ++k)
        if (v[k] > best) { best = v[k]; bi = k; }  // first-max == jnp.argmax
    return bi;
}

// exclusive in-place scan of arr[2048] by 1024 threads (each owns 2 elems).
// Works for 16|16 packed fields: per-field totals < 65536 -> no cross-field carry.
__device__ __forceinline__ void scan_inplace(int* arr, int* tmp, int* totalOut) {
    int tid = threadIdx.x;
    int lane = tid & 63, wid = tid >> 6;
    int i0 = 2 * tid, i1 = i0 + 1;
    int v0 = arr[i0], v1 = arr[i1];
    int s = v0 + v1;
    int inc = s;
#pragma unroll
    for (int off = 1; off < 64; off <<= 1) {
        int u = __shfl_up(inc, off);
        if (lane >= off) inc += u;
    }
    if (lane == 63) tmp[wid] = inc;
    __syncthreads();
    if (wid == 0) {
        int w = (lane < 16) ? tmp[lane] : 0;
        int incw = w;
#pragma unroll
        for (int off = 1; off < 16; off <<= 1) {
            int u = __shfl_up(incw, off);
            if (lane >= off) incw += u;
        }
        if (lane < 16) tmp[lane] = incw - w;  // exclusive wave bases
    }
    __syncthreads();
    int base = tmp[wid] + (inc - s);
    arr[i0] = base;
    arr[i1] = base + v0;
    if (tid == 1023) *totalOut = base + v0 + v1;
    __syncthreads();
}

__global__ __launch_bounds__(1024) void k_all(
    const float* __restrict__ probas, const float* __restrict__ clusters,
    const int* __restrict__ edges, const int* __restrict__ keypts,
    Cand* __restrict__ spill, int pmax, float* __restrict__ out) {

    extern __shared__ char smem[];
    float4*   s_cluA = (float4*)(smem + OFF_CLUA);
    float4*   s_cluB = (float4*)(smem + OFF_CLUB);
    int*      s_pk   = (int*)(smem + OFF_PK);
    int*      s_q    = (int*)(smem + OFF_Q);
    int*      s_cur  = (int*)(smem + OFF_CUR);
    uint16_t* s_csr  = (uint16_t*)(smem + OFF_CSR);
    float*    s_bc   = (float*)(smem + OFF_BC);
    uint8_t*  s_clst = (uint8_t*)(smem + OFF_CLST);
    uint16_t* s_pa   = (uint16_t*)(smem + OFF_PA);
    int*      s_tmp  = (int*)(smem + OFF_TMP);
    int*      s_hist = (int*)(smem + OFF_HIST);
    float*    s_wsum = (float*)(smem + OFF_WSUM);
    int*      s_wcnt = (int*)(smem + OFF_WCNT);
    int*      s_misc = (int*)(smem + OFF_MISC);

    int tid = threadIdx.x;

    // preload edge table into regs (overlaps cluster-staging latency)
    const int2* ed2 = (const int2*)edges;
    int2 pre[8];
#pragma unroll
    for (int it = 0; it < 8; ++it) pre[it] = ed2[tid + it * NTHR];

    s_pk[tid] = 0; s_pk[tid + 1024] = 0;
    if (tid == 0) s_misc[0] = 0;

    // ===== A1: stage clusters coalesced into LDS + per-node argmax =====
    const float4* c4 = (const float4*)clusters;
#pragma unroll
    for (int r = 0; r < 2; ++r) {
        int n = tid + r * 1024;
        float4 a = c4[2 * n], b = c4[2 * n + 1];
        s_cluA[n] = a; s_cluB[n] = b;
        s_clst[n] = (uint8_t)argmax8(a, b);
    }
    __syncthreads();
    if (tid < L_CONST)
        atomicOr((uint32_t*)&s_misc[0], 1u << s_clst[keypts[tid]]);
    __syncthreads();
    uint32_t m = (uint32_t)s_misc[0];

    // ===== A2: per-edge flag + packed counts + PRECOMPUTED bc (clusters in LDS) =====
    uint32_t af[8];  // anchor(<<2) | flag
#pragma unroll
    for (int it = 0; it < 8; ++it) {
        int e = tid + it * NTHR;
        int2 p = pre[it];
        int c0 = s_clst[p.x], c1 = s_clst[p.y];
        int f = 0;
        if ((((m >> c0) | (m >> c1)) & 1u)) f = (c0 == c1) ? 1 : 2;  // 1=pos, 2=neg
        af[it] = ((uint32_t)p.x << 2) | (uint32_t)f;
        if (f == 1)      atomicAdd(&s_pk[p.x], 1);
        else if (f == 2) atomicAdd(&s_pk[p.x], 0x10000);
        float4 a0 = s_cluA[p.x], a1 = s_cluB[p.x];
        float4 b0 = s_cluA[p.y], b1 = s_cluB[p.y];
        float s = __builtin_amdgcn_sqrtf(a0.x * b0.x);  // k ascending, matches ref order
        s += __builtin_amdgcn_sqrtf(a0.y * b0.y);
        s += __builtin_amdgcn_sqrtf(a0.z * b0.z);
        s += __builtin_amdgcn_sqrtf(a0.w * b0.w);
        s += __builtin_amdgcn_sqrtf(a1.x * b1.x);
        s += __builtin_amdgcn_sqrtf(a1.y * b1.y);
        s += __builtin_amdgcn_sqrtf(a1.z * b1.z);
        s += __builtin_amdgcn_sqrtf(a1.w * b1.w);
        s_bc[e] = s;
    }
    __syncthreads();

    // ===== B: pair counts + in-place scans =====
    {
        int i0 = 2 * tid, i1 = i0 + 1;
        int p0 = s_pk[i0], p1 = s_pk[i1];
        s_q[i0] = (p0 & 0xFFFF) * (p0 >> 16);
        s_q[i1] = (p1 & 0xFFFF) * (p1 >> 16);
    }
    __syncthreads();
    scan_inplace(s_pk, s_tmp, &s_misc[1]);
    scan_inplace(s_q, s_tmp, &s_misc[2]);
    s_cur[2 * tid] = s_pk[2 * tid];
    s_cur[2 * tid + 1] = s_pk[2 * tid + 1];
    __syncthreads();
    int nPosTot = s_misc[1] & 0xFFFF;
    int nNegTot = s_misc[1] >> 16;
    int totQ = s_misc[2];
    int P = totQ; if (P > pmax) P = pmax;

    // ===== C: CSR fill + pairAnchor table (independent LDS regions, one phase) =====
#pragma unroll
    for (int it = 0; it < 8; ++it) {
        int f = (int)(af[it] & 3u);
        int a = (int)(af[it] >> 2);
        int e = tid + it * NTHR;
        if (f == 1) {
            int old = atomicAdd(&s_cur[a], 1);
            s_csr[old & 0xFFFF] = (uint16_t)e;
        } else if (f == 2) {
            int old = atomicAdd(&s_cur[a], 0x10000);
            s_csr[nPosTot + (old >> 16)] = (uint16_t)e;
        }
    }
    for (int a = tid; a < N_CONST; a += NTHR) {
        int q0 = s_q[a];
        int q1 = (a < N_CONST - 1) ? s_q[a + 1] : totQ;
        for (int t = q0; t < q1 && t < TCAP; ++t) s_pa[t] = (uint16_t)a;
    }
    __syncthreads();

    // ===== D: one thread per valid pair; anchor via table; bc via 2 scalar reads =====
    auto make_cand = [&](int t, float& val, uint32_t& pack) {
        int a;
        if (t < TCAP) a = (int)s_pa[t];
        else {  // fallback (statistically unused)
            int lo = 0, hi = N_CONST - 1;
#pragma unroll
            for (int itr = 0; itr < 11; ++itr) {
                int mid = (lo + hi + 1) >> 1;
                if (s_q[mid] <= t) lo = mid; else hi = mid - 1;
            }
            a = lo;
        }
        int loc = t - s_q[a];
        int pk = s_pk[a];
        int pb = pk & 0xFFFF, nb = pk >> 16;
        int nextN = (a < N_CONST - 1) ? (s_pk[a + 1] >> 16) : nNegTot;
        int nn = nextN - nb;  // >= 1 for any anchor owning pairs
        int ip = loc / nn;
        int jn = loc - ip * nn;
        int i = s_csr[pb + ip];
        int j = s_csr[nPosTot + nb + jn];
        float w = 1.0f - 0.5f * (s_bc[i] + s_bc[j]);
        val = (w > 0.0f)
            ? __logf(fmaxf(w, EPS_F)) + gumbel_at((uint32_t)i * E_CONST + (uint32_t)j)
            : -INFINITY;  // ref: logw=-inf -> excluded via ok mask
        pack = ((uint32_t)i << 16) | (uint32_t)j;
    };

    float vval0 = 0.f, vval1 = 0.f, vval2 = 0.f, vval3 = 0.f;  // static-indexed (rule #20)
    uint32_t vpk0 = 0, vpk1 = 0, vpk2 = 0, vpk3 = 0;
    if (tid        < P) make_cand(tid,        vval0, vpk0);
    if (tid + 1024 < P) make_cand(tid + 1024, vval1, vpk1);
    if (tid + 2048 < P) make_cand(tid + 2048, vval2, vpk2);
    if (tid + 3072 < P) make_cand(tid + 3072, vval3, vpk3);
    for (int t = tid + RCAP; t < P; t += NTHR) {  // spill path (statistically unused)
        float v; uint32_t pk;
        make_cand(t, v, pk);
        spill[t - RCAP].val = v; spill[t - RCAP].pack = pk;
    }
    uint32_t vk0 = sortable_key(vval0), vk1 = sortable_key(vval1);
    uint32_t vk2 = sortable_key(vval2), vk3 = sortable_key(vval3);
    __syncthreads();

    // ===== E: 4-pass radix threshold (plain LDS-atomic hist; wave-0 suffix scan) =====
    uint32_t* s_prefix = (uint32_t*)&s_misc[3];
    int*      s_target = &s_misc[4];
    int M = P;
    uint32_t thr = 0;
    if (M > MAXS) {
        if (tid == 0) { *s_prefix = 0; *s_target = MAXS; }
        __syncthreads();
        for (int pass = 0; pass < 4; ++pass) {
            int shift = 24 - 8 * pass;
            if (tid < 256) s_hist[tid] = 0;
            __syncthreads();
            uint32_t pfx = *s_prefix;
            if (tid        < M && (pass == 0 || (vk0 >> (shift + 8)) == pfx)) atomicAdd(&s_hist[(vk0 >> shift) & 255], 1);
            if (tid + 1024 < M && (pass == 0 || (vk1 >> (shift + 8)) == pfx)) atomicAdd(&s_hist[(vk1 >> shift) & 255], 1);
            if (tid + 2048 < M && (pass == 0 || (vk2 >> (shift + 8)) == pfx)) atomicAdd(&s_hist[(vk2 >> shift) & 255], 1);
            if (tid + 3072 < M && (pass == 0 || (vk3 >> (shift + 8)) == pfx)) atomicAdd(&s_hist[(vk3 >> shift) & 255], 1);
            for (int t = tid + RCAP; t < M; t += NTHR) {
                uint32_t k = sortable_key(spill[t - RCAP].val);
                if (pass == 0 || (k >> (shift + 8)) == pfx)
                    atomicAdd(&s_hist[(k >> shift) & 255], 1);
            }
            __syncthreads();
            if (tid < 64) {  // wave 0: lane L owns bins 4L..4L+3, suffix-scan select
                int h0 = s_hist[4 * tid], h1 = s_hist[4 * tid + 1];
                int h2 = s_hist[4 * tid + 2], h3 = s_hist[4 * tid + 3];
                int sincl = h0 + h1 + h2 + h3;
#pragma unroll
                for (int off = 1; off < 64; off <<= 1) {
                    int v = __shfl_down(sincl, off);
                    if (tid + off < 64) sincl += v;
                }
                int excl = __shfl_down(sincl, 1);
                if (tid == 63) excl = 0;
                int suf3 = excl + h3;
                int suf2 = suf3 + h2;
                int suf1 = suf2 + h1;
                int suf0 = suf1 + h0;
                int tgt = *s_target;
                uint32_t pfxOld = *s_prefix;
                if      (suf0 >= tgt && suf1 < tgt) { *s_prefix = (pfxOld << 8) | (4u*tid+0); *s_target = tgt - suf1; }
                else if (suf1 >= tgt && suf2 < tgt) { *s_prefix = (pfxOld << 8) | (4u*tid+1); *s_target = tgt - suf2; }
                else if (suf2 >= tgt && suf3 < tgt) { *s_prefix = (pfxOld << 8) | (4u*tid+2); *s_target = tgt - suf3; }
                else if (suf3 >= tgt && excl < tgt) { *s_prefix = (pfxOld << 8) | (4u*tid+3); *s_target = tgt - excl; }
            }
            __syncthreads();
        }
        thr = *s_prefix;  // exact sortable key of the 400th-largest value
    }

    // ===== F: deterministic reduce of selected terms =====
    float mysum = 0.f;
    int myc = 0;
    auto accum = [&](int t, float v, uint32_t k, uint32_t pk) {
        if (t < M && v != -INFINITY && k >= thr) {
            int i = (int)(pk >> 16), j = (int)(pk & 0xFFFFu);
            float pi = probas[i], pj = probas[j];
            mysum += __logf(pi / (pi + pj));  // ~1e-6 abs err, threshold 1.7e-2
            myc++;
        }
    };
    accum(tid,        vval0, vk0, vpk0);
    accum(tid + 1024, vval1, vk1, vpk1);
    accum(tid + 2048, vval2, vk2, vpk2);
    accum(tid + 3072, vval3, vk3, vpk3);
    for (int t = tid + RCAP; t < M; t += NTHR) {
        Cand c = spill[t - RCAP];
        accum(t, c.val, sortable_key(c.val), c.pack);
    }
#pragma unroll
    for (int off = 32; off > 0; off >>= 1) {
        mysum += __shfl_down(mysum, off);
        myc   += __shfl_down(myc, off);
    }
    int wid = tid >> 6;
    if ((tid & 63) == 0) { s_wsum[wid] = mysum; s_wcnt[wid] = myc; }
    __syncthreads();
    if (tid == 0) {
        float s = 0.f; int c = 0;
        for (int w = 0; w < 16; ++w) { s += s_wsum[w]; c += s_wcnt[w]; }
        if (c < 1) c = 1;
        out[0] = -s / (float)c;
    }
}

extern "C" void kernel_launch(void* const* d_in, const int* in_sizes, int n_in,
                              void* d_out, int out_size, void* d_ws, size_t ws_size,
                              hipStream_t stream) {
    const float* probas   = (const float*)d_in[0];
    const float* clusters = (const float*)d_in[1];
    const int*   edges    = (const int*)d_in[2];
    const int*   keypts   = (const int*)d_in[3];
    float* out = (float*)d_out;

    Cand* spill = (Cand*)d_ws;
    int spill_cap = (int)(ws_size / sizeof(Cand));
    if (spill_cap > 61440) spill_cap = 61440;
    int pmax = RCAP + spill_cap;

    // allow >64KB dynamic LDS (idempotent host-side call; not a stream op)
    hipFuncSetAttribute((const void*)k_all,
                        hipFuncAttributeMaxDynamicSharedMemorySize, LDS_BYTES);

    k_all<<<1, NTHR, LDS_BYTES, stream>>>(probas, clusters, edges, keypts,
                                          spill, pmax, out);
}